// Round 4
// baseline (119.268 us; speedup 1.0000x reference)
//
#include <hip/hip_runtime.h>
#include <math.h>
#include <float.h>

// b=8, c=64, H=W=64, KS=8 -> P = 57*57 = 3249.
// Stage 1 per (b,c): G[m,n] = <patch_m, patch_n> over P; corr = G/(sqrt(diag)sqrt(diag)P);
//   sort 64 m per column n desc; ranks {1,9,16,24,32,40,48,55,63} -> xp[b,c,576].
// Stage 2 per b: corr2[p,q] = sum_c Xn[c,p]Xn[c,q]/64; sort 576 p per q desc; 115 ranks.
//
// R10 lesson: three k3 sort-side ablations (CE count -30%, pipe move, 2x ILP) all
//   left k3 at ~40 us -> sort is NOT the wall; fused phase 1 (Gram) is.
// R11: stage-2 split: k2 (norms) + k3a (LDS-tiled GEMM Graw = X^T X, 64x64 tiles)
//   + k3b (sort-only, 1 wave/column, reads Graw row q == column q by symmetry).
//   Gives per-phase rocprof isolation AND removes phase-1 load/FMA interleave.

#define IMGS 65

// ---- DPP helpers ----
template<int CTRL, int RM>
__device__ __forceinline__ float dpp_add(float x) {
    int o = __builtin_amdgcn_update_dpp(0, __float_as_int(x), CTRL, RM, 0xf, true);
    return x + __int_as_float(o);
}
__device__ __forceinline__ float wscan_add(float x) {
    x = dpp_add<0x111, 0xf>(x);
    x = dpp_add<0x112, 0xf>(x);
    x = dpp_add<0x114, 0xf>(x);
    x = dpp_add<0x118, 0xf>(x);
    x = dpp_add<0x142, 0xa>(x);
    x = dpp_add<0x143, 0xc>(x);
    return x;
}
template<int CTRL>
__device__ __forceinline__ float dpp_perm(float x) {
    int o = __builtin_amdgcn_update_dpp(__float_as_int(x), __float_as_int(x), CTRL, 0xf, 0xf, false);
    return __int_as_float(o);
}
#define QP_XOR1 0xB1   // [1,0,3,2]
#define QP_XOR2 0x4E   // [2,3,0,1]

// ---- xor-J lane exchange: DPP for 1/2 (VALU), ds_swizzle for 4/8/16, bpermute for 32 ----
template<int J>
__device__ __forceinline__ float shx(float x) {
    if constexpr (J == 1)       return dpp_perm<QP_XOR1>(x);
    else if constexpr (J == 2)  return dpp_perm<QP_XOR2>(x);
    else if constexpr (J <= 16)
        return __int_as_float(__builtin_amdgcn_ds_swizzle(__float_as_int(x), (J << 10) | 0x1F));
    else
        return __shfl_xor(x, 32, 64);
}
template<int J>
__device__ __forceinline__ void cex(float& v, const bool keep_max) {
    const float o = shx<J>(v);
    v = keep_max ? fmaxf(v, o) : fminf(v, o);
}
template<int DESC>
__device__ __forceinline__ void cer(float& a, float& b) {
    const float mx = fmaxf(a, b), mn = fminf(a, b);
    if constexpr (DESC) { a = mx; b = mn; } else { a = mn; b = mx; }
}
template<int DESC>
__device__ __forceinline__ void merge64(float& v, const int lane) {
    cex<32>(v, (((lane & 32) != 0) ^ DESC) != 0);
    cex<16>(v, (((lane & 16) != 0) ^ DESC) != 0);
    cex<8>(v,  (((lane &  8) != 0) ^ DESC) != 0);
    cex<4>(v,  (((lane &  4) != 0) ^ DESC) != 0);
    cex<2>(v,  (((lane &  2) != 0) ^ DESC) != 0);
    cex<1>(v,  (((lane &  1) != 0) ^ DESC) != 0);
}

__host__ __device__ constexpr int offF(int dj) { return dj * (17 - dj) / 2; }       // 36 total
__host__ __device__ constexpr int offB(int dj) { return (dj - 1) * (16 - dj) / 2; } // 28 total

// ---------------- k1: fused stage-1, pair-symmetric, canonical-G (R1 winner) ----------------
// grid = 512 (bc), block = 512 (8 waves; wave wv handles row-shift d = wv)
__global__ __launch_bounds__(512) void k1(const float* __restrict__ x,
                                          float* __restrict__ xp) {
    __shared__ float img[64 * IMGS];   // 16.6 KB
    __shared__ float G[64 * IMGS];     // canonical: G[m*65+n], m<=n

    const int t = threadIdx.x;
    const int bc = blockIdx.x;
    const float* src = x + (size_t)bc * 4096;

    #pragma unroll
    for (int k = 0; k < 2; ++k) {
        int i4 = t + k * 512;
        float4 v = ((const float4*)src)[i4];
        int fl = i4 * 4, row = fl >> 6, col = fl & 63;
        float* dd = &img[row * IMGS + col];
        dd[0] = v.x; dd[1] = v.y; dd[2] = v.z; dd[3] = v.w;
    }
    __syncthreads();

    const int wv = t >> 6, lane = t & 63;
    const int d = wv;                            // 0..7
    const int a = lane;
    const bool av = (a + d <= 63);
    const int a1 = min(a + d, 63);
    const float* r0 = &img[a * IMGS];
    const float* r1 = &img[a1 * IMGS];

    float wf[8] = {0,0,0,0,0,0,0,0}, wb[8] = {0,0,0,0,0,0,0,0};
    float sf[8], sb[8], hf[7], hb[7];
    #pragma unroll
    for (int k = 0; k < 7; ++k) { sf[k] = r1[k]; sb[k] = r0[k]; hf[k] = sf[k]; hb[k] = sb[k]; }
    #pragma unroll
    for (int c = 0; c < 7; ++c) {
        #pragma unroll
        for (int j = 0; j < 8; ++j) {
            const int u = c * 8 + j;
            sf[(j + 7) & 7] = r1[u + 7];
            sb[(j + 7) & 7] = r0[u + 7];
            const float f0 = sb[j & 7];          // r0[u]
            const float g0 = sf[j & 7];          // r1[u]
            #pragma unroll
            for (int k = 0; k < 8; ++k) wf[k] = fmaf(f0, sf[(j + k) & 7], wf[k]);
            #pragma unroll
            for (int k = 1; k < 8; ++k) wb[k] = fmaf(g0, sb[(j + k) & 7], wb[k]);
        }
    }
    {   // u = 56 (j-pattern 0)
        sf[7] = r1[63]; sb[7] = r0[63];
        const float f0 = sb[0], g0 = sf[0];
        #pragma unroll
        for (int k = 0; k < 8; ++k) wf[k] = fmaf(f0, sf[k], wf[k]);
        #pragma unroll
        for (int k = 1; k < 8; ++k) wb[k] = fmaf(g0, sb[k], wb[k]);
    }

    float Wf[36], Wb[28];
    #pragma unroll
    for (int dj = 0; dj < 8; ++dj) {
        float a0 = wf[dj];
        Wf[offF(dj)] = a0;
        #pragma unroll
        for (int st = 1; st < 8 - dj; ++st) {
            a0 += sb[st] * sf[st + dj] - hb[st - 1] * hf[st - 1 + dj];
            Wf[offF(dj) + st] = a0;
        }
    }
    #pragma unroll
    for (int dj = 1; dj < 8; ++dj) {
        float a0 = wb[dj];
        Wb[offB(dj)] = a0;
        #pragma unroll
        for (int st = 1; st < 8 - dj; ++st) {
            a0 += sf[st] * sb[st + dj] - hf[st - 1] * hb[st - 1 + dj];
            Wb[offB(dj) + st] = a0;
        }
    }

    const float msk = av ? 1.0f : 0.0f;
    #pragma unroll
    for (int i = 0; i < 36; ++i) Wf[i] = wscan_add(Wf[i] * msk);
    if (d > 0) {
        #pragma unroll
        for (int i = 0; i < 28; ++i) Wb[i] = wscan_add(Wb[i] * msk);
    }

    const bool wr = (lane >= 56) && (lane <= 63 - d);
    const int ki = lane - 56;
    #pragma unroll
    for (int dj = 0; dj < 8; ++dj) {
        #pragma unroll
        for (int st = 0; st < 8 - dj; ++st) {
            {
                float P = Wf[offF(dj) + st];
                float sl = __shfl_up(P, 57, 64);
                float S = P - (lane >= 57 ? sl : 0.0f);
                if (wr) G[(ki * 8 + st) * IMGS + ((ki + d) * 8 + st + dj)] = S;
            }
            if (d > 0 && dj > 0) {
                float P = Wb[offB(dj) + st];
                float sl = __shfl_up(P, 57, 64);
                float S = P - (lane >= 57 ? sl : 0.0f);
                if (wr) G[(ki * 8 + st + dj) * IMGS + ((ki + d) * 8 + st)] = S;
            }
        }
    }
    __syncthreads();

    const int m = lane;
    const float invm = 1.0f / fmaxf(sqrtf(G[m * 66]), 1e-12f);
    const float sc = 1.0f / 3249.0f;
    const int c0 = wv * 8;
    float v[8];
    #pragma unroll
    for (int cc = 0; cc < 8; ++cc) {
        const int col = c0 + cc;
        const int addr = (m <= col) ? m * IMGS + col : col * IMGS + m;   // symmetric read
        const float invc = __shfl(invm, col, 64);
        v[cc] = G[addr] * invm * invc * sc;
    }
    #pragma unroll
    for (int kk = 2; kk <= 64; kk <<= 1) {
        #pragma unroll
        for (int j = kk >> 1; j > 0; j >>= 1) {
            const bool upper = (lane & j) != 0;
            const bool dir0  = (lane & kk) == 0;
            const bool keep_max = dir0 ^ upper;
            float o[8];
            #pragma unroll
            for (int cc = 0; cc < 8; ++cc) {
                if (j == 1)      o[cc] = dpp_perm<QP_XOR1>(v[cc]);
                else if (j == 2) o[cc] = dpp_perm<QP_XOR2>(v[cc]);
                else             o[cc] = __shfl_xor(v[cc], j, 64);
            }
            #pragma unroll
            for (int cc = 0; cc < 8; ++cc)
                v[cc] = keep_max ? fmaxf(v[cc], o[cc]) : fminf(v[cc], o[cc]);
        }
    }
    int ridx = -1;
    if      (lane ==  1) ridx = 0; else if (lane ==  9) ridx = 1; else if (lane == 16) ridx = 2;
    else if (lane == 24) ridx = 3; else if (lane == 32) ridx = 4; else if (lane == 40) ridx = 5;
    else if (lane == 48) ridx = 6; else if (lane == 55) ridx = 7; else if (lane == 63) ridx = 8;
    if (ridx >= 0) {
        float* dst = xp + (size_t)bc * 576 + ridx * 64 + c0;
        *(float4*)&dst[0] = make_float4(v[0], v[1], v[2], v[3]);
        *(float4*)&dst[4] = make_float4(v[4], v[5], v[6], v[7]);
    }
}

// ---------------- k2: per-(b,p) inverse channel norms ----------------
// grid = 8*9, block = 64; thread p sums x^2 over 64 channels (same FMA order as before)
__global__ __launch_bounds__(64) void k2(const float* __restrict__ xp,
                                         float* __restrict__ ipL) {
    const int b = blockIdx.x / 9, pg = blockIdx.x % 9;
    const int p = pg * 64 + threadIdx.x;
    const float* xb = xp + (size_t)b * 36864;
    float sd = 0.f;
    #pragma unroll 8
    for (int c = 0; c < 64; ++c) { const float v = xb[c * 576 + p]; sd = fmaf(v, v, sd); }
    ipL[b * 576 + p] = 1.0f / fmaxf(sqrtf(sd), 1e-12f);
}

// ---------------- k3a: Graw[b] = X^T X, LDS-tiled 64x64 GEMM ----------------
// grid = 8*81, block = 256 (16x16 threads, 4x4 microtile), single K=64 pass
__global__ __launch_bounds__(256) void k3a(const float* __restrict__ xp,
                                           float* __restrict__ graw) {
    __shared__ __align__(16) float At[64][64];   // 16 KB
    __shared__ __align__(16) float Bt[64][64];   // 16 KB
    const int bid = blockIdx.x;
    const int b = bid / 81, tid = bid % 81;
    const int p0 = (tid / 9) * 64, q0 = (tid % 9) * 64;
    const float* __restrict__ xb = xp + (size_t)b * 36864;
    const int t = threadIdx.x;

    #pragma unroll
    for (int k = 0; k < 4; ++k) {
        const int f = t + k * 256;
        const int cc = f >> 4, pp4 = f & 15;
        const float4 a  = *(const float4*)(xb + cc * 576 + p0 + pp4 * 4);
        const float4 bb = *(const float4*)(xb + cc * 576 + q0 + pp4 * 4);
        *(float4*)&At[cc][pp4 * 4] = a;
        *(float4*)&Bt[cc][pp4 * 4] = bb;
    }
    __syncthreads();

    const int tx = t & 15, ty = t >> 4;
    float acc[16];
    #pragma unroll
    for (int i = 0; i < 16; ++i) acc[i] = 0.f;
    #pragma unroll
    for (int c = 0; c < 64; ++c) {
        const float4 fa = *(const float4*)&At[c][ty * 4];
        const float4 fb = *(const float4*)&Bt[c][tx * 4];
        const float va[4] = {fa.x, fa.y, fa.z, fa.w};
        const float vb[4] = {fb.x, fb.y, fb.z, fb.w};
        #pragma unroll
        for (int i = 0; i < 4; ++i)
            #pragma unroll
            for (int j = 0; j < 4; ++j)
                acc[i * 4 + j] = fmaf(va[i], vb[j], acc[i * 4 + j]);
    }
    float* go = graw + ((size_t)b * 576 + p0 + ty * 4) * 576 + q0 + tx * 4;
    #pragma unroll
    for (int i = 0; i < 4; ++i)
        *(float4*)(go + (size_t)i * 576) = make_float4(acc[i*4+0], acc[i*4+1], acc[i*4+2], acc[i*4+3]);
}

// ---------------- k3b: sort-only stage-2 (reads Graw row q == column q) ----------------
// grid = 8*144, block = 256 (4 waves; wave wv sorts column q = qg*4+wv)
__global__ __launch_bounds__(256) void k3b(const float* __restrict__ graw,
                                           const float* __restrict__ ipL,
                                           float* __restrict__ out) {
    __shared__ float rankbuf[115 * 4];
    const int t = threadIdx.x;
    const int b = blockIdx.x / 144, qg = blockIdx.x % 144;
    const int wv = t >> 6, lane = t & 63;
    const int q = qg * 4 + wv;
    const float* __restrict__ row = graw + ((size_t)b * 576 + q) * 576;
    const float* __restrict__ ipb = ipL + b * 576;
    const float ipq = ipb[q] * 0.015625f;   // /64 ; >0, order-preserving -> deferred

    float v[9];
    #pragma unroll
    for (int r = 0; r < 9; ++r)
        v[r] = row[r * 64 + lane] * ipb[r * 64 + lane];   // coalesced, L2/L3-hot

    // level 0: per-reg 64-sorts; dirs: desc {0,3,5,6}, asc {1,2,4,7,8}
    #define SSTAGE(KK, J) { \
        const bool kma = (((lane & (J)) != 0) == ((lane & (KK)) == 0)); \
        cex<J>(v[0], !kma); cex<J>(v[1],  kma); cex<J>(v[2],  kma); cex<J>(v[3], !kma); \
        cex<J>(v[4],  kma); cex<J>(v[5], !kma); cex<J>(v[6], !kma); cex<J>(v[7],  kma); \
        cex<J>(v[8],  kma); }
    SSTAGE(2, 1)
    SSTAGE(4, 2)   SSTAGE(4, 1)
    SSTAGE(8, 4)   SSTAGE(8, 2)   SSTAGE(8, 1)
    SSTAGE(16, 8)  SSTAGE(16, 4)  SSTAGE(16, 2)  SSTAGE(16, 1)
    SSTAGE(32, 16) SSTAGE(32, 8)  SSTAGE(32, 4)  SSTAGE(32, 2)  SSTAGE(32, 1)
    SSTAGE(64, 32) SSTAGE(64, 16) SSTAGE(64, 8)  SSTAGE(64, 4)  SSTAGE(64, 2) SSTAGE(64, 1)
    #undef SSTAGE

    // level 1: (0,1)->desc128, (2,3)->asc128, (4,5)->asc128, (6,7)->desc128
    cer<1>(v[0], v[1]); cer<0>(v[2], v[3]); cer<0>(v[4], v[5]); cer<1>(v[6], v[7]);
    merge64<1>(v[0], lane); merge64<1>(v[1], lane);
    merge64<0>(v[2], lane); merge64<0>(v[3], lane);
    merge64<0>(v[4], lane); merge64<0>(v[5], lane);
    merge64<1>(v[6], lane); merge64<1>(v[7], lane);

    // level 2: (0-3)->desc256, (4-7)->asc256
    cer<1>(v[0], v[2]); cer<1>(v[1], v[3]);
    cer<1>(v[0], v[1]); cer<1>(v[2], v[3]);
    merge64<1>(v[0], lane); merge64<1>(v[1], lane); merge64<1>(v[2], lane); merge64<1>(v[3], lane);
    cer<0>(v[4], v[6]); cer<0>(v[5], v[7]);
    cer<0>(v[4], v[5]); cer<0>(v[6], v[7]);
    merge64<0>(v[4], lane); merge64<0>(v[5], lane); merge64<0>(v[6], lane); merge64<0>(v[7], lane);

    // level 3: (0-7)->desc512
    cer<1>(v[0], v[4]); cer<1>(v[1], v[5]); cer<1>(v[2], v[6]); cer<1>(v[3], v[7]);
    cer<1>(v[0], v[2]); cer<1>(v[1], v[3]); cer<1>(v[4], v[6]); cer<1>(v[5], v[7]);
    cer<1>(v[0], v[1]); cer<1>(v[2], v[3]); cer<1>(v[4], v[5]); cer<1>(v[6], v[7]);
    #pragma unroll
    for (int r = 0; r < 8; ++r) merge64<1>(v[r], lane);

    // level 4: desc512 + asc64(reg8) -> desc576 (virtual 1024 merge, -inf pads folded)
    cer<1>(v[7], v[8]);
    cer<1>(v[0], v[4]); cer<1>(v[1], v[5]); cer<1>(v[2], v[6]); cer<1>(v[3], v[7]);
    cer<1>(v[0], v[2]); cer<1>(v[1], v[3]); cer<1>(v[4], v[6]); cer<1>(v[5], v[7]);
    cer<1>(v[0], v[1]); cer<1>(v[2], v[3]); cer<1>(v[4], v[5]); cer<1>(v[6], v[7]);
    #pragma unroll
    for (int r = 0; r < 8; ++r) merge64<1>(v[r], lane);
    merge64<1>(v[8], lane);

    // ---- extract ranks = round(linspace(1,575,115)) == 1 + 5i + (2i)/57 + ((2i%57)>=29)
    #pragma unroll
    for (int r = 0; r < 9; ++r) {
        const int pos = r * 64 + lane;
        const int rr0 = (int)((float)pos * 0.1993f);
        #pragma unroll
        for (int dd = -1; dd <= 2; ++dd) {
            const int cand = rr0 + dd;
            if (cand >= 0 && cand < 115) {
                const int ti = 2 * cand;
                const int rk = 1 + 5 * cand + ti / 57 + ((ti % 57) >= 29 ? 1 : 0);
                if (rk == pos) rankbuf[cand * 4 + wv] = v[r] * ipq;
            }
        }
    }
    __syncthreads();
    for (int i = t; i < 115 * 4; i += 256) {
        const int rr = i >> 2, qq = i & 3;
        out[(size_t)b * 66240 + rr * 576 + qg * 4 + qq] = rankbuf[rr * 4 + qq];
    }
}

extern "C" void kernel_launch(void* const* d_in, const int* in_sizes, int n_in,
                              void* d_out, int out_size, void* d_ws, size_t ws_size,
                              hipStream_t stream) {
    const float* x = (const float*)d_in[0];   // [8,64,64,64] fp32
    float* out = (float*)d_out;               // [8,115,24,24] fp32
    float* xp   = (float*)d_ws;               // [8,64,576]   = 294912 floats
    float* ipL  = xp + 294912;                // [8,576]      = 4608 floats
    float* graw = xp + 299520;                // [8,576,576]  = 2654208 floats (~10.6 MB)

    k1 <<<dim3(512),  dim3(512), 0, stream>>>(x, xp);
    k2 <<<dim3(72),   dim3(64),  0, stream>>>(xp, ipL);
    k3a<<<dim3(648),  dim3(256), 0, stream>>>(xp, graw);
    k3b<<<dim3(1152), dim3(256), 0, stream>>>(graw, ipL, out);
}

// Round 6
// 111.412 us; speedup vs baseline: 1.0705x; 1.0705x over previous
//
#include <hip/hip_runtime.h>
#include <math.h>
#include <float.h>

// b=8, c=64, H=W=64, KS=8 -> P = 57*57 = 3249.
// Stage 1 per (b,c): G[m,n] = <patch_m, patch_n> over P; corr = G/(sqrt(diag)sqrt(diag)P);
//   sort 64 m per column n desc; ranks {1,9,16,24,32,40,48,55,63} -> xp[b,c,576].
// Stage 2 per b: corr2[p,q] = sum_c Xn[c,p]Xn[c,q]/64; sort 576 p per q desc; 115 ranks.
//
// R11 lesson: splitting stage-2 (GEMM + sort-only kernels) LOST to the fused k3:
//   phase 1 was already overlapped with sort waves; split added gaps + HBM trip.
// R12 (resubmit; R5 bench was an infra failure): revert to R1 config (fused k3
//   @40us, k1 @30us) + exec-masked selects. Every CE was max+min+cndmask
//   (3 VALU/reg); the stage predicate is shared by all regs, so
//   if(km){N max}else{N min} = 2 VALU/reg + ~3 SALU/stage. Applied to k1 sort64
//   and k3's whole merge tree.

#define IMGS 65

// ---- DPP helpers ----
template<int CTRL, int RM>
__device__ __forceinline__ float dpp_add(float x) {
    int o = __builtin_amdgcn_update_dpp(0, __float_as_int(x), CTRL, RM, 0xf, true);
    return x + __int_as_float(o);
}
__device__ __forceinline__ float wscan_add(float x) {
    x = dpp_add<0x111, 0xf>(x);
    x = dpp_add<0x112, 0xf>(x);
    x = dpp_add<0x114, 0xf>(x);
    x = dpp_add<0x118, 0xf>(x);
    x = dpp_add<0x142, 0xa>(x);
    x = dpp_add<0x143, 0xc>(x);
    return x;
}
template<int CTRL>
__device__ __forceinline__ float dpp_perm(float x) {
    int o = __builtin_amdgcn_update_dpp(__float_as_int(x), __float_as_int(x), CTRL, 0xf, 0xf, false);
    return __int_as_float(o);
}
#define QP_XOR1 0xB1   // [1,0,3,2]
#define QP_XOR2 0x4E   // [2,3,0,1]

// ---- xor-J lane exchange: DPP for 1/2 (VALU), ds_swizzle for 4/8/16, bpermute for 32 ----
template<int J>
__device__ __forceinline__ float shx(float x) {
    if constexpr (J == 1)       return dpp_perm<QP_XOR1>(x);
    else if constexpr (J == 2)  return dpp_perm<QP_XOR2>(x);
    else if constexpr (J <= 16)
        return __int_as_float(__builtin_amdgcn_ds_swizzle(__float_as_int(x), (J << 10) | 0x1F));
    else
        return __shfl_xor(x, 32, 64);
}

// in-lane compare-exchange between two regs; DESC: a (lower position) keeps max
template<int DESC>
__device__ __forceinline__ void cer(float& a, float& b) {
    const float mx = fmaxf(a, b), mn = fminf(a, b);
    if constexpr (DESC) { a = mx; b = mn; } else { a = mn; b = mx; }
}

// ---- batched bitonic stage with exec-branched select ----
// AM bit r set = reg r is an "ascending" slot (takes max when kma).
// "descending" slots (bit clear) take min when kma. kma = (lane&J on) == (lane&KK off);
// KK=0 folds to the merge-stage predicate (lane&J)!=0.
template<int KK, int J, int AM, int N>
__device__ __forceinline__ void sstage(float* v, const int lane) {
    float o[N];
    #pragma unroll
    for (int r = 0; r < N; ++r) o[r] = shx<J>(v[r]);
    const bool kma = (((lane & J) != 0) == ((lane & KK) == 0));
    if (kma) {
        #pragma unroll
        for (int r = 0; r < N; ++r) v[r] = ((AM >> r) & 1) ? fmaxf(v[r], o[r]) : fminf(v[r], o[r]);
    } else {
        #pragma unroll
        for (int r = 0; r < N; ++r) v[r] = ((AM >> r) & 1) ? fminf(v[r], o[r]) : fmaxf(v[r], o[r]);
    }
}
// batched 64-wide bitonic merge (6 stages), directions per reg via AM
template<int AM, int N>
__device__ __forceinline__ void mergeL(float* v, const int lane) {
    sstage<0, 32, AM, N>(v, lane);
    sstage<0, 16, AM, N>(v, lane);
    sstage<0,  8, AM, N>(v, lane);
    sstage<0,  4, AM, N>(v, lane);
    sstage<0,  2, AM, N>(v, lane);
    sstage<0,  1, AM, N>(v, lane);
}

__host__ __device__ constexpr int offF(int dj) { return dj * (17 - dj) / 2; }       // 36 total
__host__ __device__ constexpr int offB(int dj) { return (dj - 1) * (16 - dj) / 2; } // 28 total

// ---------------- k1: fused stage-1, pair-symmetric, canonical-G ----------------
// grid = 512 (bc), block = 512 (8 waves; wave wv handles row-shift d = wv)
__global__ __launch_bounds__(512) void k1(const float* __restrict__ x,
                                          float* __restrict__ xp) {
    __shared__ float img[64 * IMGS];   // 16.6 KB
    __shared__ float G[64 * IMGS];     // canonical: G[m*65+n], m<=n

    const int t = threadIdx.x;
    const int bc = blockIdx.x;
    const float* src = x + (size_t)bc * 4096;

    #pragma unroll
    for (int k = 0; k < 2; ++k) {
        int i4 = t + k * 512;
        float4 v = ((const float4*)src)[i4];
        int fl = i4 * 4, row = fl >> 6, col = fl & 63;
        float* dd = &img[row * IMGS + col];
        dd[0] = v.x; dd[1] = v.y; dd[2] = v.z; dd[3] = v.w;
    }
    __syncthreads();

    const int wv = t >> 6, lane = t & 63;
    const int d = wv;                            // 0..7
    const int a = lane;
    const bool av = (a + d <= 63);
    const int a1 = min(a + d, 63);
    const float* r0 = &img[a * IMGS];
    const float* r1 = &img[a1 * IMGS];

    // ---- FMA phase: wf[k]=sum r0[u]*r1[u+k], wb[k]=sum r1[u]*r0[u+k]  (u=0..56) ----
    float wf[8] = {0,0,0,0,0,0,0,0}, wb[8] = {0,0,0,0,0,0,0,0};
    float sf[8], sb[8], hf[7], hb[7];
    #pragma unroll
    for (int k = 0; k < 7; ++k) { sf[k] = r1[k]; sb[k] = r0[k]; hf[k] = sf[k]; hb[k] = sb[k]; }
    #pragma unroll
    for (int c = 0; c < 7; ++c) {
        #pragma unroll
        for (int j = 0; j < 8; ++j) {
            const int u = c * 8 + j;
            sf[(j + 7) & 7] = r1[u + 7];
            sb[(j + 7) & 7] = r0[u + 7];
            const float f0 = sb[j & 7];          // r0[u]
            const float g0 = sf[j & 7];          // r1[u]
            #pragma unroll
            for (int k = 0; k < 8; ++k) wf[k] = fmaf(f0, sf[(j + k) & 7], wf[k]);
            #pragma unroll
            for (int k = 1; k < 8; ++k) wb[k] = fmaf(g0, sb[(j + k) & 7], wb[k]);
        }
    }
    {   // u = 56 (j-pattern 0)
        sf[7] = r1[63]; sb[7] = r0[63];
        const float f0 = sb[0], g0 = sf[0];
        #pragma unroll
        for (int k = 0; k < 8; ++k) wf[k] = fmaf(f0, sf[k], wf[k]);
        #pragma unroll
        for (int k = 1; k < 8; ++k) wb[k] = fmaf(g0, sb[k], wb[k]);
    }
    // now sf[k] = r1[56+k], sb[k] = r0[56+k]  (tails); hf/hb = heads

    // ---- slide over st (all indices compile-time) ----
    float Wf[36], Wb[28];
    #pragma unroll
    for (int dj = 0; dj < 8; ++dj) {
        float a0 = wf[dj];
        Wf[offF(dj)] = a0;
        #pragma unroll
        for (int st = 1; st < 8 - dj; ++st) {
            a0 += sb[st] * sf[st + dj] - hb[st - 1] * hf[st - 1 + dj];
            Wf[offF(dj) + st] = a0;
        }
    }
    #pragma unroll
    for (int dj = 1; dj < 8; ++dj) {
        float a0 = wb[dj];
        Wb[offB(dj)] = a0;
        #pragma unroll
        for (int st = 1; st < 8 - dj; ++st) {
            a0 += sf[st] * sb[st + dj] - hf[st - 1] * hb[st - 1 + dj];
            Wb[offB(dj) + st] = a0;
        }
    }

    // ---- mask invalid rows, DPP prefix-scan over lanes (rows a) ----
    const float msk = av ? 1.0f : 0.0f;
    #pragma unroll
    for (int i = 0; i < 36; ++i) Wf[i] = wscan_add(Wf[i] * msk);
    if (d > 0) {
        #pragma unroll
        for (int i = 0; i < 28; ++i) Wb[i] = wscan_add(Wb[i] * msk);
    }

    // ---- extract: S(ki) on lane ki+56 = P[lane] - P[lane-57]; write canonical G ----
    const bool wr = (lane >= 56) && (lane <= 63 - d);
    const int ki = lane - 56;
    #pragma unroll
    for (int dj = 0; dj < 8; ++dj) {
        #pragma unroll
        for (int st = 0; st < 8 - dj; ++st) {
            {
                float P = Wf[offF(dj) + st];
                float sl = __shfl_up(P, 57, 64);
                float S = P - (lane >= 57 ? sl : 0.0f);
                if (wr) G[(ki * 8 + st) * IMGS + ((ki + d) * 8 + st + dj)] = S;
            }
            if (d > 0 && dj > 0) {
                float P = Wb[offB(dj) + st];
                float sl = __shfl_up(P, 57, 64);
                float S = P - (lane >= 57 ? sl : 0.0f);
                if (wr) G[(ki * 8 + st + dj) * IMGS + ((ki + d) * 8 + st)] = S;
            }
        }
    }
    __syncthreads();

    // ---- normalize + batched sort64 (wave wv: columns wv*8..wv*8+7) ----
    const int m = lane;
    const float invm = 1.0f / fmaxf(sqrtf(G[m * 66]), 1e-12f);
    const float sc = 1.0f / 3249.0f;
    const int c0 = wv * 8;
    float v[8];
    #pragma unroll
    for (int cc = 0; cc < 8; ++cc) {
        const int col = c0 + cc;
        const int addr = (m <= col) ? m * IMGS + col : col * IMGS + m;   // symmetric read
        const float invc = __shfl(invm, col, 64);
        v[cc] = G[addr] * invm * invc * sc;
    }
    // sort64 descending over lanes, batched over 8 columns, exec-branched selects.
    // original keep_max = ((lane&KK)==0) ^ ((lane&J)!=0) = !kma -> all regs "desc" (AM=0).
    sstage<2, 1, 0, 8>(v, lane);
    sstage<4, 2, 0, 8>(v, lane);   sstage<4, 1, 0, 8>(v, lane);
    sstage<8, 4, 0, 8>(v, lane);   sstage<8, 2, 0, 8>(v, lane);   sstage<8, 1, 0, 8>(v, lane);
    sstage<16, 8, 0, 8>(v, lane);  sstage<16, 4, 0, 8>(v, lane);  sstage<16, 2, 0, 8>(v, lane);
    sstage<16, 1, 0, 8>(v, lane);
    sstage<32, 16, 0, 8>(v, lane); sstage<32, 8, 0, 8>(v, lane);  sstage<32, 4, 0, 8>(v, lane);
    sstage<32, 2, 0, 8>(v, lane);  sstage<32, 1, 0, 8>(v, lane);
    sstage<64, 32, 0, 8>(v, lane); sstage<64, 16, 0, 8>(v, lane); sstage<64, 8, 0, 8>(v, lane);
    sstage<64, 4, 0, 8>(v, lane);  sstage<64, 2, 0, 8>(v, lane);  sstage<64, 1, 0, 8>(v, lane);
    // ranks2 = {1,9,16,24,32,40,48,55,63}
    int ridx = -1;
    if      (lane ==  1) ridx = 0; else if (lane ==  9) ridx = 1; else if (lane == 16) ridx = 2;
    else if (lane == 24) ridx = 3; else if (lane == 32) ridx = 4; else if (lane == 40) ridx = 5;
    else if (lane == 48) ridx = 6; else if (lane == 55) ridx = 7; else if (lane == 63) ridx = 8;
    if (ridx >= 0) {
        float* dst = xp + (size_t)bc * 576 + ridx * 64 + c0;
        *(float4*)&dst[0] = make_float4(v[0], v[1], v[2], v[3]);
        *(float4*)&dst[4] = make_float4(v[4], v[5], v[6], v[7]);
    }
}

// ---------------- k3: fused stage-2 (Gram columns + norms + sort + ranks) ----------------
// grid = 8*64 (b x q-group of 9), block = 576 (9 waves; wave sorts column q0+wv)
__global__ __launch_bounds__(576) void k3(const float* __restrict__ xp,
                                          float* __restrict__ out) {
    __shared__ __align__(16) float sbuf[9 * 580];   // raw corr columns, stride 580
    __shared__ __align__(16) float ipL[576];        // per-p inverse channel norms
    __shared__ float rankbuf[115 * 12];
    const int t = threadIdx.x;
    const int b = blockIdx.x >> 6, qg = blockIdx.x & 63;
    const int q0 = qg * 9;
    const float* __restrict__ xb = xp + (size_t)b * 36864;

    // ---- phase 1: thread p computes raw corr2 col entries for 9 q's + own norm ----
    {
        const int p = t;
        float acc[9] = {0,0,0,0,0,0,0,0,0};
        float sd = 0.f;
        #pragma unroll 8
        for (int c = 0; c < 64; ++c) {
            const float xv = xb[c * 576 + p];                  // coalesced vector load
            sd = fmaf(xv, xv, sd);
            #pragma unroll
            for (int qq = 0; qq < 9; ++qq)
                acc[qq] = fmaf(xv, xb[c * 576 + q0 + qq], acc[qq]);  // uniform -> s_load
        }
        ipL[p] = 1.0f / fmaxf(sqrtf(sd), 1e-12f);
        #pragma unroll
        for (int qq = 0; qq < 9; ++qq) sbuf[qq * 580 + p] = acc[qq];
    }
    __syncthreads();

    // ---- phase 2: wave wv sorts column q = q0+wv, 9-reg merge-tree (no padding) ----
    const int wv = t >> 6, lane = t & 63;
    const float ipq = ipL[q0 + wv] * 0.015625f;   // /64 ; >0, order-preserving -> deferred
    float v[9];
    {
        const float* sb2 = &sbuf[wv * 580];
        #pragma unroll
        for (int r = 0; r < 9; ++r)
            v[r] = sb2[r * 64 + lane] * ipL[r * 64 + lane];   // stride-1: conflict-free
    }

    // level 0: per-reg 64-sorts; dirs: desc {0,3,5,6}, asc {1,2,4,7,8} -> AM=406
    constexpr int AM0 = (1<<1)|(1<<2)|(1<<4)|(1<<7)|(1<<8);   // 406
    sstage<2, 1, AM0, 9>(v, lane);
    sstage<4, 2, AM0, 9>(v, lane);   sstage<4, 1, AM0, 9>(v, lane);
    sstage<8, 4, AM0, 9>(v, lane);   sstage<8, 2, AM0, 9>(v, lane);   sstage<8, 1, AM0, 9>(v, lane);
    sstage<16, 8, AM0, 9>(v, lane);  sstage<16, 4, AM0, 9>(v, lane);  sstage<16, 2, AM0, 9>(v, lane);
    sstage<16, 1, AM0, 9>(v, lane);
    sstage<32, 16, AM0, 9>(v, lane); sstage<32, 8, AM0, 9>(v, lane);  sstage<32, 4, AM0, 9>(v, lane);
    sstage<32, 2, AM0, 9>(v, lane);  sstage<32, 1, AM0, 9>(v, lane);
    sstage<64, 32, AM0, 9>(v, lane); sstage<64, 16, AM0, 9>(v, lane); sstage<64, 8, AM0, 9>(v, lane);
    sstage<64, 4, AM0, 9>(v, lane);  sstage<64, 2, AM0, 9>(v, lane);  sstage<64, 1, AM0, 9>(v, lane);

    // level 1: (0,1)->desc128, (2,3)->asc128, (4,5)->asc128, (6,7)->desc128
    cer<1>(v[0], v[1]); cer<0>(v[2], v[3]); cer<0>(v[4], v[5]); cer<1>(v[6], v[7]);
    mergeL<(1<<2)|(1<<3)|(1<<4)|(1<<5), 8>(v, lane);   // asc regs 2..5

    // level 2: (0-3)->desc256, (4-7)->asc256
    cer<1>(v[0], v[2]); cer<1>(v[1], v[3]);
    cer<1>(v[0], v[1]); cer<1>(v[2], v[3]);
    cer<0>(v[4], v[6]); cer<0>(v[5], v[7]);
    cer<0>(v[4], v[5]); cer<0>(v[6], v[7]);
    mergeL<(1<<4)|(1<<5)|(1<<6)|(1<<7), 8>(v, lane);   // asc regs 4..7

    // level 3: (0-7)->desc512
    cer<1>(v[0], v[4]); cer<1>(v[1], v[5]); cer<1>(v[2], v[6]); cer<1>(v[3], v[7]);
    cer<1>(v[0], v[2]); cer<1>(v[1], v[3]); cer<1>(v[4], v[6]); cer<1>(v[5], v[7]);
    cer<1>(v[0], v[1]); cer<1>(v[2], v[3]); cer<1>(v[4], v[5]); cer<1>(v[6], v[7]);
    mergeL<0, 8>(v, lane);                             // all desc

    // level 4: desc512 + asc64(reg8) -> desc576 (virtual 1024 merge, -inf pads folded)
    cer<1>(v[7], v[8]);
    cer<1>(v[0], v[4]); cer<1>(v[1], v[5]); cer<1>(v[2], v[6]); cer<1>(v[3], v[7]);
    cer<1>(v[0], v[2]); cer<1>(v[1], v[3]); cer<1>(v[4], v[6]); cer<1>(v[5], v[7]);
    cer<1>(v[0], v[1]); cer<1>(v[2], v[3]); cer<1>(v[4], v[5]); cer<1>(v[6], v[7]);
    mergeL<0, 9>(v, lane);                             // all 9 regs, desc

    // ---- extract ranks = round(linspace(1,575,115)) == 1 + 5i + (2i)/57 + ((2i%57)>=29)
    #pragma unroll
    for (int r = 0; r < 9; ++r) {
        const int pos = r * 64 + lane;
        const int rr0 = (int)((float)pos * 0.1993f);
        #pragma unroll
        for (int dd = -1; dd <= 2; ++dd) {
            const int cand = rr0 + dd;
            if (cand >= 0 && cand < 115) {
                const int ti = 2 * cand;
                const int rk = 1 + 5 * cand + ti / 57 + ((ti % 57) >= 29 ? 1 : 0);
                if (rk == pos) rankbuf[cand * 12 + wv] = v[r] * ipq;
            }
        }
    }
    __syncthreads();
    for (int i = t; i < 115 * 9; i += 576) {
        const int rr = i / 9, qq = i - rr * 9;
        out[(size_t)b * 66240 + rr * 576 + q0 + qq] = rankbuf[rr * 12 + qq];
    }
}

extern "C" void kernel_launch(void* const* d_in, const int* in_sizes, int n_in,
                              void* d_out, int out_size, void* d_ws, size_t ws_size,
                              hipStream_t stream) {
    const float* x = (const float*)d_in[0];   // [8,64,64,64] fp32
    float* out = (float*)d_out;               // [8,115,24,24] fp32
    float* xp = (float*)d_ws;                 // [8,64,576] = 294912 floats (~1.2 MB)

    k1<<<dim3(512), dim3(512), 0, stream>>>(x, xp);
    k3<<<dim3(512), dim3(576), 0, stream>>>(xp, out);
}